// Round 2
// baseline (958.313 us; speedup 1.0000x reference)
//
#include <hip/hip_runtime.h>

typedef __attribute__((ext_vector_type(8))) short short8;
typedef __attribute__((ext_vector_type(4))) float f32x4;

#define T_LEN 320

__device__ inline unsigned short bf16_rne(float x) {
    union { float f; unsigned u; } a; a.f = x;
    unsigned r = a.u + 0x7fffu + ((a.u >> 16) & 1u);
    return (unsigned short)(r >> 16);
}
__device__ inline float bf16_to_f(unsigned short h) {
    union { unsigned u; float f; } a; a.u = ((unsigned)h) << 16;
    return a.f;
}
// 3-way split: x = h + m + l + O(2^-27 |x|)
__device__ inline void split3(float x, unsigned short &h, unsigned short &m, unsigned short &l) {
    h = bf16_rne(x);
    const float r1 = x - bf16_to_f(h);
    m = bf16_rne(r1);
    l = bf16_rne(r1 - bf16_to_f(m));
}

// ---------------------------------------------------------------------------
// Kernel 1: conv1(5,64->32)+bn1+relu -> conv2(3,32->16)+bn2+relu
// 3-way-split bf16 MFMA (6 products: hh,hm,mh,hl,lh,mm) -> f32-grade accuracy.
// Each block: 2 batch rows, 5 chunks of 64 timesteps.
// Output e_ws layout: (B, 16, T) f32.
// ---------------------------------------------------------------------------
__global__ __launch_bounds__(256, 2) void geo_alif_conv_kernel(
    const float* __restrict__ x_eeg,
    const float* __restrict__ k1g, const float* __restrict__ c1bias,
    const float* __restrict__ bn1s, const float* __restrict__ bn1b,
    const float* __restrict__ bn1m, const float* __restrict__ bn1v,
    const float* __restrict__ k2g, const float* __restrict__ c2bias,
    const float* __restrict__ bn2s, const float* __restrict__ bn2b,
    const float* __restrict__ bn2m, const float* __restrict__ bn2v,
    float* __restrict__ e_ws)
{
    // x slab: t in [t0-3, t0+66], 70 positions, 64 ch, bf16 h/m/l, XOR-swizzled 8-el blocks
    __shared__ unsigned short xh[2][70][64];
    __shared__ unsigned short xm[2][70][64];
    __shared__ unsigned short xl[2][70][64];
    // conv1 out slab: t in [t0-1, t0+64], 66 positions, 32 ch, bf16 h/m/l
    __shared__ unsigned short c1h[2][66][32];
    __shared__ unsigned short c1m[2][66][32];
    __shared__ unsigned short c1l[2][66][32];

    const int tid  = threadIdx.x;
    const int lane = tid & 63;
    const int wv   = tid >> 6;        // wave 0..3
    const int row  = wv >> 1;         // batch row within block (0..1)
    const int nh   = wv & 1;          // conv1 n-half (co 0..15 / 16..31); also conv2 m-half
    const int lcol = lane & 15;
    const int lg   = lane >> 4;       // 0..3

    // ---- per-wave register B-fragments for conv1 (K = w*64+ci, 10 K-steps of 32) ----
    short8 w1h[10], w1m[10], w1l[10];
#pragma unroll
    for (int ks = 0; ks < 10; ++ks) {
        const int w = ks >> 1;
        const int cib = (ks & 1) * 32 + lg * 8;
        short8 hh, mm, ll;
#pragma unroll
        for (int j = 0; j < 8; ++j) {
            float kv = k1g[(w * 64 + cib + j) * 32 + (nh * 16 + lcol)];
            unsigned short h, m, l; split3(kv, h, m, l);
            hh[j] = (short)h; mm[j] = (short)m; ll[j] = (short)l;
        }
        w1h[ks] = hh; w1m[ks] = mm; w1l[ks] = ll;
    }
    // ---- conv2 B-fragments (K = w*32+ci, 3 K-steps), identical in every wave ----
    short8 w2h[3], w2m[3], w2l[3];
#pragma unroll
    for (int ks = 0; ks < 3; ++ks) {
        const int cib = lg * 8;
        short8 hh, mm, ll;
#pragma unroll
        for (int j = 0; j < 8; ++j) {
            float kv = k2g[(ks * 32 + cib + j) * 16 + lcol];
            unsigned short h, m, l; split3(kv, h, m, l);
            hh[j] = (short)h; mm[j] = (short)m; ll[j] = (short)l;
        }
        w2h[ks] = hh; w2m[ks] = mm; w2l[ks] = ll;
    }
    // ---- folded BN constants for this lane's output columns ----
    const int co1 = nh * 16 + lcol;
    const float s1 = bn1s[co1] * (1.0f / sqrtf(bn1v[co1] + 1e-5f));
    const float b1 = bn1b[co1] + (c1bias[co1] - bn1m[co1]) * s1;
    const float s2 = bn2s[lcol] * (1.0f / sqrtf(bn2v[lcol] + 1e-5f));
    const float b2 = bn2b[lcol] + (c2bias[lcol] - bn2m[lcol]) * s2;

    const int b0 = blockIdx.x * 2;

    for (int ch = 0; ch < 5; ++ch) {
        const int t0 = ch * 64;
        // ---- stage x slab (f32 -> bf16 h/m/l, swizzled) ----
        for (int fi = tid; fi < 2 * 70 * 16; fi += 256) {
            const int r   = fi / (70 * 16);
            const int rem = fi - r * (70 * 16);
            const int s   = rem >> 4;
            const int cq  = rem & 15;            // 4-float group
            const int tabs = t0 - 3 + s;
            float4 v = {0.f, 0.f, 0.f, 0.f};
            if (tabs >= 0 && tabs < T_LEN)
                v = *reinterpret_cast<const float4*>(
                    x_eeg + ((size_t)(b0 + r) * T_LEN + tabs) * 64 + cq * 4);
            unsigned short h0,m0,l0,h1,m1,l1,h2,m2,l2,h3,m3,l3;
            split3(v.x, h0, m0, l0); split3(v.y, h1, m1, l1);
            split3(v.z, h2, m2, l2); split3(v.w, h3, m3, l3);
            const int pblk = (cq >> 1) ^ (s & 7);
            const int off  = pblk * 8 + (cq & 1) * 4;
            ushort4 hv = {h0, h1, h2, h3};
            ushort4 mv = {m0, m1, m2, m3};
            ushort4 lv = {l0, l1, l2, l3};
            *reinterpret_cast<ushort4*>(&xh[r][s][off]) = hv;
            *reinterpret_cast<ushort4*>(&xm[r][s][off]) = mv;
            *reinterpret_cast<ushort4*>(&xl[r][s][off]) = lv;
        }
        __syncthreads();

        // ---- conv1: tile rows [t0-1, t0+78] (66 valid), 5 m-frags, N=16 per wave ----
        {
            f32x4 acc[5];
#pragma unroll
            for (int mi = 0; mi < 5; ++mi) acc[mi] = (f32x4){0.f,0.f,0.f,0.f};
#pragma unroll
            for (int ks = 0; ks < 10; ++ks) {
                const int w  = ks >> 1;
                const int lb = (ks & 1) * 4 + lg;      // logical 8-el block (ci/8)
#pragma unroll
                for (int mi = 0; mi < 5; ++mi) {
                    int s = mi * 16 + lcol + w;        // slab index (base t0-3 vs out base t0-1)
                    s = (s > 69) ? 69 : s;             // clamp for masked rows
                    const int off = ((lb ^ (s & 7)) * 8);
                    short8 ah = *reinterpret_cast<const short8*>(&xh[row][s][off]);
                    short8 am = *reinterpret_cast<const short8*>(&xm[row][s][off]);
                    short8 al = *reinterpret_cast<const short8*>(&xl[row][s][off]);
                    acc[mi] = __builtin_amdgcn_mfma_f32_16x16x32_bf16(ah, w1h[ks], acc[mi], 0, 0, 0);
                    acc[mi] = __builtin_amdgcn_mfma_f32_16x16x32_bf16(ah, w1m[ks], acc[mi], 0, 0, 0);
                    acc[mi] = __builtin_amdgcn_mfma_f32_16x16x32_bf16(am, w1h[ks], acc[mi], 0, 0, 0);
                    acc[mi] = __builtin_amdgcn_mfma_f32_16x16x32_bf16(ah, w1l[ks], acc[mi], 0, 0, 0);
                    acc[mi] = __builtin_amdgcn_mfma_f32_16x16x32_bf16(al, w1h[ks], acc[mi], 0, 0, 0);
                    acc[mi] = __builtin_amdgcn_mfma_f32_16x16x32_bf16(am, w1m[ks], acc[mi], 0, 0, 0);
                }
            }
            // bn1 + relu + split -> c1 slab (zero for t outside [0,T): conv2 padding)
#pragma unroll
            for (int mi = 0; mi < 5; ++mi) {
                f32x4 c = acc[mi];
#pragma unroll
                for (int reg = 0; reg < 4; ++reg) {
                    const int rl = mi * 16 + lg * 4 + reg;
                    if (rl < 66) {
                        const int tabs = t0 - 1 + rl;
                        float val = 0.f;
                        if (tabs >= 0 && tabs < T_LEN)
                            val = fmaxf(c[reg] * s1 + b1, 0.f);
                        unsigned short h, m, l; split3(val, h, m, l);
                        const int pb  = (co1 >> 3) ^ (rl & 3);
                        const int off = pb * 8 + (co1 & 7);
                        c1h[row][rl][off] = h;
                        c1m[row][rl][off] = m;
                        c1l[row][rl][off] = l;
                    }
                }
            }
        }
        __syncthreads();

        // ---- conv2: wave = (row, m-half of 32 t); 2 m-frags, N=16 ----
        {
            f32x4 d[2];
#pragma unroll
            for (int mi = 0; mi < 2; ++mi) d[mi] = (f32x4){0.f,0.f,0.f,0.f};
#pragma unroll
            for (int ks = 0; ks < 3; ++ks) {          // tap w
#pragma unroll
                for (int mi = 0; mi < 2; ++mi) {
                    const int rl2  = nh * 32 + mi * 16 + lcol;  // 0..63
                    const int sidx = rl2 + ks;                  // 0..65
                    const int off  = ((lg ^ (sidx & 3)) * 8);
                    short8 ah = *reinterpret_cast<const short8*>(&c1h[row][sidx][off]);
                    short8 am = *reinterpret_cast<const short8*>(&c1m[row][sidx][off]);
                    short8 al = *reinterpret_cast<const short8*>(&c1l[row][sidx][off]);
                    d[mi] = __builtin_amdgcn_mfma_f32_16x16x32_bf16(ah, w2h[ks], d[mi], 0, 0, 0);
                    d[mi] = __builtin_amdgcn_mfma_f32_16x16x32_bf16(ah, w2m[ks], d[mi], 0, 0, 0);
                    d[mi] = __builtin_amdgcn_mfma_f32_16x16x32_bf16(am, w2h[ks], d[mi], 0, 0, 0);
                    d[mi] = __builtin_amdgcn_mfma_f32_16x16x32_bf16(ah, w2l[ks], d[mi], 0, 0, 0);
                    d[mi] = __builtin_amdgcn_mfma_f32_16x16x32_bf16(al, w2h[ks], d[mi], 0, 0, 0);
                    d[mi] = __builtin_amdgcn_mfma_f32_16x16x32_bf16(am, w2m[ks], d[mi], 0, 0, 0);
                }
            }
            // bn2 + relu -> e_ws (B,16,T), float4 stores (4 consecutive t per lane)
#pragma unroll
            for (int mi = 0; mi < 2; ++mi) {
                f32x4 c = d[mi];
                float4 ov;
                ov.x = fmaxf(c[0] * s2 + b2, 0.f);
                ov.y = fmaxf(c[1] * s2 + b2, 0.f);
                ov.z = fmaxf(c[2] * s2 + b2, 0.f);
                ov.w = fmaxf(c[3] * s2 + b2, 0.f);
                const int t = t0 + nh * 32 + mi * 16 + lg * 4;
                *reinterpret_cast<float4*>(
                    e_ws + ((size_t)(b0 + row) * 16 + lcol) * T_LEN + t) = ov;
            }
        }
        __syncthreads();
    }
}

// ---------------------------------------------------------------------------
// Kernel 2: geo gate + ALIF scan + windowed diff-pool + fc1 + fc2
// Block: 16 batch rows x 16 hidden = 256 threads. Grid: 256.
// ---------------------------------------------------------------------------
__global__ __launch_bounds__(256) void geo_alif_scan_kernel(
    const float* __restrict__ e_ws, const float* __restrict__ x_geo,
    const float* __restrict__ geoW, const float* __restrict__ geob,
    const float* __restrict__ gam,
    const float* __restrict__ fc1W, const float* __restrict__ fc1b,
    const float* __restrict__ fc2W, const float* __restrict__ fc2b,
    float* __restrict__ out)
{
    __shared__ float gW[18][16];
    __shared__ float geo_s[16][16][16];   // [row][t_local][h]
    __shared__ float dp[16][160];         // [row][h*10+w]
    __shared__ float h1s[16][64];

    const int tid = threadIdx.x;
    for (int i = tid; i < 288; i += 256) gW[i / 16][i & 15] = geoW[i];
    __syncthreads();

    const int r = tid >> 4, h = tid & 15;
    const int b = blockIdx.x * 16 + r;
    const float* ep = e_ws + ((size_t)b * 16 + h) * T_LEN;
    const float gmv = gam[h];

    float mem = 0.f, eta = 0.f, li = 0.f, prev = 0.f, acc = 0.f;

    for (int c = 0; c < 20; ++c) {
        // geo_mod for 16-step chunk: thread (rg, tl) computes all 16 h
        {
            const int rg = tid >> 4, tl = tid & 15;
            const int t = c * 16 + tl;
            const float* xg = x_geo + ((size_t)(blockIdx.x * 16 + rg) * T_LEN + t) * 18;
            float xv[18];
#pragma unroll
            for (int i = 0; i < 18; ++i) xv[i] = xg[i];
#pragma unroll
            for (int hh = 0; hh < 16; ++hh) {
                float a = geob[hh];
#pragma unroll
                for (int i = 0; i < 18; ++i) a = fmaf(xv[i], gW[i][hh], a);
                geo_s[rg][tl][hh] = 1.f / (1.f + expf(-a));
            }
        }
        __syncthreads();

        const float* ec = ep + c * 16;
#pragma unroll
        for (int q = 0; q < 4; ++q) {
            float4 ev = *reinterpret_cast<const float4*>(ec + q * 4);
            float evs[4] = {ev.x, ev.y, ev.z, ev.w};
#pragma unroll
            for (int u = 0; u < 4; ++u) {
                const int tt = c * 16 + q * 4 + u;
                const float g = geo_s[r][q * 4 + u][h];
                eta = 0.36f * eta + 0.64f * prev;
                const float th = 0.5f + 1.8f * eta - gmv * g;
                mem = 0.8f * mem + evs[u];
                const bool sp = (mem >= th);
                const float spk = sp ? 1.f : 0.f;
                prev = spk;
                mem = sp ? 0.f : mem;
                li = 0.9f * li + spk;
                acc += ((tt & 31) < 16) ? -li : li;
                if ((tt & 31) == 31) {
                    dp[r][h * 10 + (tt >> 5)] = acc * 0.0625f;
                    acc = 0.f;
                }
            }
        }
        __syncthreads();
    }

    // fc1: 16 rows x 64 outputs
    {
        const int rr = tid >> 4, j0 = tid & 15;
        float a0 = fc1b[j0], a1 = fc1b[j0 + 16], a2 = fc1b[j0 + 32], a3 = fc1b[j0 + 48];
        for (int f = 0; f < 160; ++f) {
            const float d = dp[rr][f];
            a0 = fmaf(d, fc1W[f * 64 + j0],      a0);
            a1 = fmaf(d, fc1W[f * 64 + j0 + 16], a1);
            a2 = fmaf(d, fc1W[f * 64 + j0 + 32], a2);
            a3 = fmaf(d, fc1W[f * 64 + j0 + 48], a3);
        }
        h1s[rr][j0]      = fmaxf(a0, 0.f);
        h1s[rr][j0 + 16] = fmaxf(a1, 0.f);
        h1s[rr][j0 + 32] = fmaxf(a2, 0.f);
        h1s[rr][j0 + 48] = fmaxf(a3, 0.f);
    }
    __syncthreads();

    // fc2: 16 rows x 4 outputs
    if (tid < 64) {
        const int rr = tid >> 2, o = tid & 3;
        float a = fc2b[o];
#pragma unroll
        for (int j = 0; j < 64; ++j) a = fmaf(h1s[rr][j], fc2W[j * 4 + o], a);
        out[((size_t)(blockIdx.x * 16 + rr)) * 4 + o] = a;
    }
}

extern "C" void kernel_launch(void* const* d_in, const int* in_sizes, int n_in,
                              void* d_out, int out_size, void* d_ws, size_t ws_size,
                              hipStream_t stream) {
    (void)in_sizes; (void)n_in; (void)out_size; (void)ws_size;
    const float* x_eeg = (const float*)d_in[0];
    const float* x_geo = (const float*)d_in[1];
    const float* k1    = (const float*)d_in[2];
    const float* c1b   = (const float*)d_in[3];
    const float* bn1s  = (const float*)d_in[4];
    const float* bn1b  = (const float*)d_in[5];
    const float* bn1m  = (const float*)d_in[6];
    const float* bn1v  = (const float*)d_in[7];
    const float* k2    = (const float*)d_in[8];
    const float* c2b   = (const float*)d_in[9];
    const float* bn2s  = (const float*)d_in[10];
    const float* bn2b  = (const float*)d_in[11];
    const float* bn2m  = (const float*)d_in[12];
    const float* bn2v  = (const float*)d_in[13];
    const float* geoW  = (const float*)d_in[14];
    const float* geob  = (const float*)d_in[15];
    const float* gam   = (const float*)d_in[16];
    const float* fc1W  = (const float*)d_in[17];
    const float* fc1b  = (const float*)d_in[18];
    const float* fc2W  = (const float*)d_in[19];
    const float* fc2b  = (const float*)d_in[20];

    float* e_ws = (float*)d_ws;   // needs 4096*16*320*4 = 83,886,080 bytes

    geo_alif_conv_kernel<<<2048, 256, 0, stream>>>(
        x_eeg, k1, c1b, bn1s, bn1b, bn1m, bn1v,
        k2, c2b, bn2s, bn2b, bn2m, bn2v, e_ws);

    geo_alif_scan_kernel<<<256, 256, 0, stream>>>(
        e_ws, x_geo, geoW, geob, gam, fc1W, fc1b, fc2W, fc2b, (float*)d_out);
}

// Round 3
// 527.132 us; speedup vs baseline: 1.8180x; 1.8180x over previous
//
#include <hip/hip_runtime.h>

typedef __attribute__((ext_vector_type(8))) short short8;
typedef __attribute__((ext_vector_type(4))) float f32x4;

#define T_LEN 320

__device__ inline unsigned short bf16_rne(float x) {
    union { float f; unsigned u; } a; a.f = x;
    unsigned r = a.u + 0x7fffu + ((a.u >> 16) & 1u);
    return (unsigned short)(r >> 16);
}
__device__ inline float bf16_to_f(unsigned short h) {
    union { unsigned u; float f; } a; a.u = ((unsigned)h) << 16;
    return a.f;
}
// 3-way split: x = h + m + l + O(2^-27 |x|)
__device__ inline void split3(float x, unsigned short &h, unsigned short &m, unsigned short &l) {
    h = bf16_rne(x);
    const float r1 = x - bf16_to_f(h);
    m = bf16_rne(r1);
    l = bf16_rne(r1 - bf16_to_f(m));
}

// ---------------------------------------------------------------------------
// Kernel 1: conv1(5,64->32)+bn1+relu -> conv2(3,32->16)+bn2+relu
// 3-way-split bf16 MFMA (6 products). Wave-specialized roles to avoid spills:
//   waves (nh, kq): kq=0 conv1 ks{0..2} + epilogue; kq=1 conv1 ks{3..6};
//   kq=2 conv1 ks{7..9}; kq=3 conv2 specialist.
// One batch row per block; 5 chunks of 64 t. Output e_ws (B,16,T) f32.
// ---------------------------------------------------------------------------
struct ConvSmem {
    unsigned short xh[70][64], xm[70][64], xl[70][64];   // x slab, swizzled
    unsigned short c1h[66][32], c1m[66][32], c1l[66][32];// conv1 out slab
    float redbuf[2][2][5][64][4];                        // partial acc: [nh][src][mi][lane][reg]
};

__device__ __forceinline__ void stage_x(ConvSmem& sm, const float* __restrict__ xrow,
                                        int t0, int start, int stride) {
    for (int fi = start; fi < 70 * 16; fi += stride) {
        const int s = fi >> 4, cq = fi & 15;
        const int tabs = t0 - 3 + s;
        float4 v = {0.f, 0.f, 0.f, 0.f};
        if (tabs >= 0 && tabs < T_LEN)
            v = *reinterpret_cast<const float4*>(xrow + (size_t)tabs * 64 + cq * 4);
        unsigned short h0,m0,l0,h1,m1,l1,h2,m2,l2,h3,m3,l3;
        split3(v.x, h0, m0, l0); split3(v.y, h1, m1, l1);
        split3(v.z, h2, m2, l2); split3(v.w, h3, m3, l3);
        const int off = (((cq >> 1) ^ (s & 7)) * 8) + (cq & 1) * 4;
        ushort4 hv = {h0, h1, h2, h3};
        ushort4 mv = {m0, m1, m2, m3};
        ushort4 lv = {l0, l1, l2, l3};
        *reinterpret_cast<ushort4*>(&sm.xh[s][off]) = hv;
        *reinterpret_cast<ushort4*>(&sm.xm[s][off]) = mv;
        *reinterpret_cast<ushort4*>(&sm.xl[s][off]) = lv;
    }
}

template<int NKS, bool EPI>
__device__ __forceinline__ void conv1_role(ConvSmem& sm, const float* __restrict__ xrow,
                                           const float* __restrict__ k1g,
                                           float s1, float b1,
                                           int tid, int lane, int nh, int ksb, int src) {
    const int lcol = lane & 15, lg = lane >> 4;
    const int co1 = nh * 16 + lcol;

    short8 w1h[NKS], w1m[NKS], w1l[NKS];
#pragma unroll
    for (int i = 0; i < NKS; ++i) {
        const int ks = ksb + i;
        const int w = ks >> 1, cib = (ks & 1) * 32 + lg * 8;
        short8 hh, mv, lv;
#pragma unroll
        for (int j = 0; j < 8; ++j) {
            float kv = k1g[(w * 64 + cib + j) * 32 + co1];
            unsigned short h, m, l; split3(kv, h, m, l);
            hh[j] = (short)h; mv[j] = (short)m; lv[j] = (short)l;
        }
        w1h[i] = hh; w1m[i] = mv; w1l[i] = lv;
    }

    for (int ch = 0; ch < 5; ++ch) {
        const int t0 = ch * 64;
        f32x4 acc[5];
#pragma unroll
        for (int mi = 0; mi < 5; ++mi) acc[mi] = (f32x4){0.f, 0.f, 0.f, 0.f};

#pragma unroll
        for (int i = 0; i < NKS; ++i) {
            const int ks = ksb + i;
            const int w = ks >> 1, lb = (ks & 1) * 4 + lg;
#pragma unroll
            for (int mi = 0; mi < 5; ++mi) {
                int s = mi * 16 + lcol + w;
                if (s > 69) s = 69;                       // rows >=66 discarded later
                const int off = ((lb ^ (s & 7)) * 8);
                short8 ah = *reinterpret_cast<const short8*>(&sm.xh[s][off]);
                short8 am = *reinterpret_cast<const short8*>(&sm.xm[s][off]);
                short8 al = *reinterpret_cast<const short8*>(&sm.xl[s][off]);
                acc[mi] = __builtin_amdgcn_mfma_f32_16x16x32_bf16(ah, w1h[i], acc[mi], 0, 0, 0);
                acc[mi] = __builtin_amdgcn_mfma_f32_16x16x32_bf16(ah, w1m[i], acc[mi], 0, 0, 0);
                acc[mi] = __builtin_amdgcn_mfma_f32_16x16x32_bf16(am, w1h[i], acc[mi], 0, 0, 0);
                acc[mi] = __builtin_amdgcn_mfma_f32_16x16x32_bf16(ah, w1l[i], acc[mi], 0, 0, 0);
                acc[mi] = __builtin_amdgcn_mfma_f32_16x16x32_bf16(al, w1h[i], acc[mi], 0, 0, 0);
                acc[mi] = __builtin_amdgcn_mfma_f32_16x16x32_bf16(am, w1m[i], acc[mi], 0, 0, 0);
            }
        }
        if (!EPI) {
#pragma unroll
            for (int mi = 0; mi < 5; ++mi)
                *reinterpret_cast<f32x4*>(&sm.redbuf[nh][src][mi][lane][0]) = acc[mi];
        }
        __syncthreads();   // B2: partials visible; x slab free

        if (EPI) {
            // sum partials, bn1+relu, 3-way split -> c1 slab
#pragma unroll
            for (int mi = 0; mi < 5; ++mi) {
                f32x4 c = acc[mi]
                    + *reinterpret_cast<const f32x4*>(&sm.redbuf[nh][0][mi][lane][0])
                    + *reinterpret_cast<const f32x4*>(&sm.redbuf[nh][1][mi][lane][0]);
#pragma unroll
                for (int reg = 0; reg < 4; ++reg) {
                    const int rl = mi * 16 + lg * 4 + reg;
                    if (rl < 66) {
                        const int tabs = t0 - 1 + rl;
                        float val = 0.f;
                        if (tabs >= 0 && tabs < T_LEN)
                            val = fmaxf(c[reg] * s1 + b1, 0.f);
                        unsigned short h, m, l; split3(val, h, m, l);
                        const int off2 = (((co1 >> 3) ^ (rl & 3)) * 8) + (co1 & 7);
                        sm.c1h[rl][off2] = h;
                        sm.c1m[rl][off2] = m;
                        sm.c1l[rl][off2] = l;
                    }
                }
            }
        } else if (ch < 4) {
            stage_x(sm, xrow, t0 + 64, tid - 128, 384);
        }
        __syncthreads();   // B3: c1 + next x slab ready
    }
}

__device__ __forceinline__ void conv2_do(ConvSmem& sm, float* __restrict__ erow, int t0p,
                                         const short8* w2h, const short8* w2m, const short8* w2l,
                                         float s2, float b2, int lane, int nh) {
    const int lcol = lane & 15, lg = lane >> 4;
    f32x4 d[2];
#pragma unroll
    for (int mi = 0; mi < 2; ++mi) d[mi] = (f32x4){0.f, 0.f, 0.f, 0.f};
#pragma unroll
    for (int ks = 0; ks < 3; ++ks) {
#pragma unroll
        for (int mi = 0; mi < 2; ++mi) {
            const int sidx = nh * 32 + mi * 16 + lcol + ks;     // 0..65
            const int off = ((lg ^ (sidx & 3)) * 8);
            short8 ah = *reinterpret_cast<const short8*>(&sm.c1h[sidx][off]);
            short8 am = *reinterpret_cast<const short8*>(&sm.c1m[sidx][off]);
            short8 al = *reinterpret_cast<const short8*>(&sm.c1l[sidx][off]);
            d[mi] = __builtin_amdgcn_mfma_f32_16x16x32_bf16(ah, w2h[ks], d[mi], 0, 0, 0);
            d[mi] = __builtin_amdgcn_mfma_f32_16x16x32_bf16(ah, w2m[ks], d[mi], 0, 0, 0);
            d[mi] = __builtin_amdgcn_mfma_f32_16x16x32_bf16(am, w2h[ks], d[mi], 0, 0, 0);
            d[mi] = __builtin_amdgcn_mfma_f32_16x16x32_bf16(ah, w2l[ks], d[mi], 0, 0, 0);
            d[mi] = __builtin_amdgcn_mfma_f32_16x16x32_bf16(al, w2h[ks], d[mi], 0, 0, 0);
            d[mi] = __builtin_amdgcn_mfma_f32_16x16x32_bf16(am, w2m[ks], d[mi], 0, 0, 0);
        }
    }
#pragma unroll
    for (int mi = 0; mi < 2; ++mi) {
        float4 ov;
        ov.x = fmaxf(d[mi][0] * s2 + b2, 0.f);
        ov.y = fmaxf(d[mi][1] * s2 + b2, 0.f);
        ov.z = fmaxf(d[mi][2] * s2 + b2, 0.f);
        ov.w = fmaxf(d[mi][3] * s2 + b2, 0.f);
        const int t = t0p + nh * 32 + mi * 16 + lg * 4;
        *reinterpret_cast<float4*>(erow + (size_t)lcol * T_LEN + t) = ov;
    }
}

__device__ __forceinline__ void conv2_role(ConvSmem& sm, const float* __restrict__ xrow,
                                           float* __restrict__ erow,
                                           const float* __restrict__ k2g,
                                           const float* __restrict__ c2bias,
                                           const float* __restrict__ bn2s,
                                           const float* __restrict__ bn2b,
                                           const float* __restrict__ bn2m,
                                           const float* __restrict__ bn2v,
                                           int tid, int lane, int nh) {
    const int lcol = lane & 15, lg = lane >> 4;
    short8 w2h[3], w2m[3], w2l[3];
#pragma unroll
    for (int ks = 0; ks < 3; ++ks) {
        const int cib = lg * 8;
        short8 hh, mv, lv;
#pragma unroll
        for (int j = 0; j < 8; ++j) {
            float kv = k2g[(ks * 32 + cib + j) * 16 + lcol];
            unsigned short h, m, l; split3(kv, h, m, l);
            hh[j] = (short)h; mv[j] = (short)m; lv[j] = (short)l;
        }
        w2h[ks] = hh; w2m[ks] = mv; w2l[ks] = lv;
    }
    const float s2 = bn2s[lcol] * (1.0f / sqrtf(bn2v[lcol] + 1e-5f));
    const float b2 = bn2b[lcol] + (c2bias[lcol] - bn2m[lcol]) * s2;

    for (int ch = 0; ch < 5; ++ch) {
        if (ch > 0) conv2_do(sm, erow, (ch - 1) * 64, w2h, w2m, w2l, s2, b2, lane, nh);
        __syncthreads();   // B2
        if (ch < 4) stage_x(sm, xrow, ch * 64 + 64, tid - 128, 384);
        __syncthreads();   // B3
    }
    conv2_do(sm, erow, 256, w2h, w2m, w2l, s2, b2, lane, nh);   // tail chunk
}

__global__ __launch_bounds__(512, 4) void geo_alif_conv_kernel(
    const float* __restrict__ x_eeg,
    const float* __restrict__ k1g, const float* __restrict__ c1bias,
    const float* __restrict__ bn1s, const float* __restrict__ bn1b,
    const float* __restrict__ bn1m, const float* __restrict__ bn1v,
    const float* __restrict__ k2g, const float* __restrict__ c2bias,
    const float* __restrict__ bn2s, const float* __restrict__ bn2b,
    const float* __restrict__ bn2m, const float* __restrict__ bn2v,
    float* __restrict__ e_ws)
{
    __shared__ ConvSmem sm;
    const int tid = threadIdx.x, lane = tid & 63;
    const int wv = tid >> 6, nh = wv & 1, kq = wv >> 1;
    const float* xrow = x_eeg + (size_t)blockIdx.x * (T_LEN * 64);
    float* erow = e_ws + (size_t)blockIdx.x * (16 * T_LEN);

    stage_x(sm, xrow, 0, tid, 512);   // prologue: chunk 0
    __syncthreads();

    if (kq == 0) {
        const int co1 = nh * 16 + (lane & 15);
        const float s1 = bn1s[co1] * (1.0f / sqrtf(bn1v[co1] + 1e-5f));
        const float b1 = bn1b[co1] + (c1bias[co1] - bn1m[co1]) * s1;
        conv1_role<3, true>(sm, xrow, k1g, s1, b1, tid, lane, nh, 0, -1);
    } else if (kq == 1) {
        conv1_role<4, false>(sm, xrow, k1g, 0.f, 0.f, tid, lane, nh, 3, 0);
    } else if (kq == 2) {
        conv1_role<3, false>(sm, xrow, k1g, 0.f, 0.f, tid, lane, nh, 7, 1);
    } else {
        conv2_role(sm, xrow, erow, k2g, c2bias, bn2s, bn2b, bn2m, bn2v, tid, lane, nh);
    }
}

// ---------------------------------------------------------------------------
// Kernel 2: geo gate + ALIF scan + windowed diff-pool + fc1 + fc2
// Block: 16 batch rows x 16 hidden = 256 threads. Grid: 256.
// ---------------------------------------------------------------------------
__global__ __launch_bounds__(256) void geo_alif_scan_kernel(
    const float* __restrict__ e_ws, const float* __restrict__ x_geo,
    const float* __restrict__ geoW, const float* __restrict__ geob,
    const float* __restrict__ gam,
    const float* __restrict__ fc1W, const float* __restrict__ fc1b,
    const float* __restrict__ fc2W, const float* __restrict__ fc2b,
    float* __restrict__ out)
{
    __shared__ float gW[18][16];
    __shared__ float geo_s[16][16][16];   // [row][t_local][h]
    __shared__ float dp[16][160];         // [row][h*10+w]
    __shared__ float h1s[16][64];

    const int tid = threadIdx.x;
    for (int i = tid; i < 288; i += 256) gW[i / 16][i & 15] = geoW[i];
    __syncthreads();

    const int r = tid >> 4, h = tid & 15;
    const int b = blockIdx.x * 16 + r;
    const float* ep = e_ws + ((size_t)b * 16 + h) * T_LEN;
    const float gmv = gam[h];

    float mem = 0.f, eta = 0.f, li = 0.f, prev = 0.f, acc = 0.f;

    for (int c = 0; c < 20; ++c) {
        {
            const int rg = tid >> 4, tl = tid & 15;
            const int t = c * 16 + tl;
            const float* xg = x_geo + ((size_t)(blockIdx.x * 16 + rg) * T_LEN + t) * 18;
            float xv[18];
#pragma unroll
            for (int i = 0; i < 18; ++i) xv[i] = xg[i];
#pragma unroll
            for (int hh = 0; hh < 16; ++hh) {
                float a = geob[hh];
#pragma unroll
                for (int i = 0; i < 18; ++i) a = fmaf(xv[i], gW[i][hh], a);
                geo_s[rg][tl][hh] = 1.f / (1.f + expf(-a));
            }
        }
        __syncthreads();

        const float* ec = ep + c * 16;
#pragma unroll
        for (int q = 0; q < 4; ++q) {
            float4 ev = *reinterpret_cast<const float4*>(ec + q * 4);
            float evs[4] = {ev.x, ev.y, ev.z, ev.w};
#pragma unroll
            for (int u = 0; u < 4; ++u) {
                const int tt = c * 16 + q * 4 + u;
                const float g = geo_s[r][q * 4 + u][h];
                eta = 0.36f * eta + 0.64f * prev;
                const float th = 0.5f + 1.8f * eta - gmv * g;
                mem = 0.8f * mem + evs[u];
                const bool sp = (mem >= th);
                const float spk = sp ? 1.f : 0.f;
                prev = spk;
                mem = sp ? 0.f : mem;
                li = 0.9f * li + spk;
                acc += ((tt & 31) < 16) ? -li : li;
                if ((tt & 31) == 31) {
                    dp[r][h * 10 + (tt >> 5)] = acc * 0.0625f;
                    acc = 0.f;
                }
            }
        }
        __syncthreads();
    }

    {
        const int rr = tid >> 4, j0 = tid & 15;
        float a0 = fc1b[j0], a1 = fc1b[j0 + 16], a2 = fc1b[j0 + 32], a3 = fc1b[j0 + 48];
        for (int f = 0; f < 160; ++f) {
            const float d = dp[rr][f];
            a0 = fmaf(d, fc1W[f * 64 + j0],      a0);
            a1 = fmaf(d, fc1W[f * 64 + j0 + 16], a1);
            a2 = fmaf(d, fc1W[f * 64 + j0 + 32], a2);
            a3 = fmaf(d, fc1W[f * 64 + j0 + 48], a3);
        }
        h1s[rr][j0]      = fmaxf(a0, 0.f);
        h1s[rr][j0 + 16] = fmaxf(a1, 0.f);
        h1s[rr][j0 + 32] = fmaxf(a2, 0.f);
        h1s[rr][j0 + 48] = fmaxf(a3, 0.f);
    }
    __syncthreads();

    if (tid < 64) {
        const int rr = tid >> 2, o = tid & 3;
        float a = fc2b[o];
#pragma unroll
        for (int j = 0; j < 64; ++j) a = fmaf(h1s[rr][j], fc2W[j * 4 + o], a);
        out[((size_t)(blockIdx.x * 16 + rr)) * 4 + o] = a;
    }
}

extern "C" void kernel_launch(void* const* d_in, const int* in_sizes, int n_in,
                              void* d_out, int out_size, void* d_ws, size_t ws_size,
                              hipStream_t stream) {
    (void)in_sizes; (void)n_in; (void)out_size; (void)ws_size;
    const float* x_eeg = (const float*)d_in[0];
    const float* x_geo = (const float*)d_in[1];
    const float* k1    = (const float*)d_in[2];
    const float* c1b   = (const float*)d_in[3];
    const float* bn1s  = (const float*)d_in[4];
    const float* bn1b  = (const float*)d_in[5];
    const float* bn1m  = (const float*)d_in[6];
    const float* bn1v  = (const float*)d_in[7];
    const float* k2    = (const float*)d_in[8];
    const float* c2b   = (const float*)d_in[9];
    const float* bn2s  = (const float*)d_in[10];
    const float* bn2b  = (const float*)d_in[11];
    const float* bn2m  = (const float*)d_in[12];
    const float* bn2v  = (const float*)d_in[13];
    const float* geoW  = (const float*)d_in[14];
    const float* geob  = (const float*)d_in[15];
    const float* gam   = (const float*)d_in[16];
    const float* fc1W  = (const float*)d_in[17];
    const float* fc1b  = (const float*)d_in[18];
    const float* fc2W  = (const float*)d_in[19];
    const float* fc2b  = (const float*)d_in[20];

    float* e_ws = (float*)d_ws;   // 4096*16*320*4 = 83,886,080 bytes

    geo_alif_conv_kernel<<<4096, 512, 0, stream>>>(
        x_eeg, k1, c1b, bn1s, bn1b, bn1m, bn1v,
        k2, c2b, bn2s, bn2b, bn2m, bn2v, e_ws);

    geo_alif_scan_kernel<<<256, 256, 0, stream>>>(
        e_ws, x_geo, geoW, geob, gam, fc1W, fc1b, fc2W, fc2b, (float*)d_out);
}